// Round 10
// baseline (585.339 us; speedup 1.0000x reference)
//
#include <hip/hip_runtime.h>

#define BN_EPS 1e-5f

__device__ __forceinline__ unsigned short f32_to_bf16(float f) {
    unsigned u = __float_as_uint(f);
    u += 0x7fffu + ((u >> 16) & 1u);   // round to nearest even
    return (unsigned short)(u >> 16);
}
__device__ __forceinline__ float bf16_lo(unsigned v) {
    return __uint_as_float(v << 16);
}
__device__ __forceinline__ float bf16_hi(unsigned v) {
    return __uint_as_float(v & 0xffff0000u);
}

// ===========================================================================
// CSR construction (by dst): rank pass -> 3-phase scan -> atomic-free fill
// ===========================================================================
__global__ __launch_bounds__(256) void rank_kernel(
    const int* __restrict__ dst, int* __restrict__ deg,
    int* __restrict__ rank, int E)
{
    int i = blockIdx.x * 256 + threadIdx.x;
    if (i < E) rank[i] = atomicAdd(&deg[dst[i]], 1);
}

__global__ __launch_bounds__(256) void scan_part1(
    const int* __restrict__ deg, int* __restrict__ blockSums, int N)
{
    __shared__ int sm[256];
    int t = threadIdx.x;
    int i0 = blockIdx.x * 512 + t * 2;
    int a = (i0     < N) ? deg[i0]     : 0;
    int b = (i0 + 1 < N) ? deg[i0 + 1] : 0;
    sm[t] = a + b;
    __syncthreads();
    for (int off = 128; off > 0; off >>= 1) {
        if (t < off) sm[t] += sm[t + off];
        __syncthreads();
    }
    if (t == 0) blockSums[blockIdx.x] = sm[0];
}

__global__ __launch_bounds__(256) void scan_part2(
    const int* __restrict__ blockSums, int* __restrict__ blockOff, int NB)
{
    __shared__ int sm[256];
    int t = threadIdx.x;
    sm[t] = (t < NB) ? blockSums[t] : 0;
    __syncthreads();
    for (int off = 1; off < 256; off <<= 1) {
        int v = (t >= off) ? sm[t - off] : 0;
        __syncthreads();
        sm[t] += v;
        __syncthreads();
    }
    if (t < NB) blockOff[t] = (t > 0) ? sm[t - 1] : 0;
}

__global__ __launch_bounds__(256) void scan_part3(
    const int* __restrict__ deg, const int* __restrict__ blockOff,
    int* __restrict__ row_start, int N, int E)
{
    __shared__ int sm[256];
    int t = threadIdx.x;
    int i0 = blockIdx.x * 512 + t * 2;
    int a = (i0     < N) ? deg[i0]     : 0;
    int b = (i0 + 1 < N) ? deg[i0 + 1] : 0;
    sm[t] = a + b;
    __syncthreads();
    for (int off = 1; off < 256; off <<= 1) {
        int v = (t >= off) ? sm[t - off] : 0;
        __syncthreads();
        sm[t] += v;
        __syncthreads();
    }
    int excl = blockOff[blockIdx.x] + ((t > 0) ? sm[t - 1] : 0);
    if (i0 < N)     row_start[i0]     = excl;
    if (i0 + 1 < N) row_start[i0 + 1] = excl + a;
    if (blockIdx.x == 0 && t == 0) row_start[N] = E;
}

__global__ __launch_bounds__(256) void fill_pass2(
    const int* __restrict__ src, const int* __restrict__ dst,
    const float* __restrict__ ew, const int* __restrict__ rank,
    const int* __restrict__ row_start, uint2* __restrict__ einfo, int E)
{
    int i = blockIdx.x * 256 + threadIdx.x;
    if (i < E) {
        int pos = row_start[dst[i]] + rank[i];
        uint2 p;
        p.x = (unsigned)src[i];
        p.y = __float_as_uint(ew[i]);
        einfo[pos] = p;
    }
}

// ===========================================================================
// Register-tiled GEMM: out[N][64] = A[N][K] @ W[K][64] (+bias)
// BF16OUT: packed-bf16 gather table out. STATS: fused BN sum/sumsq reduce.
// sA rows padded +4 floats to break rr-stride bank aliasing.
// ===========================================================================
template<int K, bool BF16OUT, bool STATS>
__global__ __launch_bounds__(256) void gemm64_kernel(
    const float* __restrict__ A, const float* __restrict__ W,
    const float* __restrict__ bias, void* __restrict__ out,
    float* __restrict__ stats, int N)
{
    __shared__ float sA[64][K + 4];
    __shared__ float sW[K][64];

    const int tid = threadIdx.x;
    const int r0  = blockIdx.x * 64;
    constexpr int C4 = K / 4;

    for (int i = tid; i < K * 16; i += 256)
        reinterpret_cast<float4*>(&sW[0][0])[i] =
            reinterpret_cast<const float4*>(W)[i];
    for (int i = tid; i < 64 * C4; i += 256) {
        int r  = i / C4;
        int c4 = i % C4;
        float4 v = make_float4(0.f, 0.f, 0.f, 0.f);
        if (r0 + r < N)
            v = reinterpret_cast<const float4*>(A + (size_t)(r0 + r) * K)[c4];
        reinterpret_cast<float4*>(&sA[r][0])[c4] = v;
    }
    __syncthreads();

    const int rr = (tid >> 4) * 4;
    const int cc = (tid & 15) * 4;

    float4 bv = make_float4(0.f, 0.f, 0.f, 0.f);
    if (bias) bv = *reinterpret_cast<const float4*>(bias + cc);

    float acc[4][4];
    #pragma unroll
    for (int i = 0; i < 4; ++i) {
        acc[i][0] = bv.x; acc[i][1] = bv.y; acc[i][2] = bv.z; acc[i][3] = bv.w;
    }

    #pragma unroll 2
    for (int k = 0; k < K; k += 4) {
        float4 w0 = *reinterpret_cast<const float4*>(&sW[k + 0][cc]);
        float4 w1 = *reinterpret_cast<const float4*>(&sW[k + 1][cc]);
        float4 w2 = *reinterpret_cast<const float4*>(&sW[k + 2][cc]);
        float4 w3 = *reinterpret_cast<const float4*>(&sW[k + 3][cc]);
        #pragma unroll
        for (int i = 0; i < 4; ++i) {
            float4 av = *reinterpret_cast<const float4*>(&sA[rr + i][k]);
            acc[i][0] = fmaf(av.x, w0.x, fmaf(av.y, w1.x, fmaf(av.z, w2.x, fmaf(av.w, w3.x, acc[i][0]))));
            acc[i][1] = fmaf(av.x, w0.y, fmaf(av.y, w1.y, fmaf(av.z, w2.y, fmaf(av.w, w3.y, acc[i][1]))));
            acc[i][2] = fmaf(av.x, w0.z, fmaf(av.y, w1.z, fmaf(av.z, w2.z, fmaf(av.w, w3.z, acc[i][2]))));
            acc[i][3] = fmaf(av.x, w0.w, fmaf(av.y, w1.w, fmaf(av.z, w2.w, fmaf(av.w, w3.w, acc[i][3]))));
        }
    }

    #pragma unroll
    for (int i = 0; i < 4; ++i) {
        int r = r0 + rr + i;
        if (r < N) {
            if (BF16OUT) {
                ushort4 o;
                o.x = f32_to_bf16(acc[i][0]);
                o.y = f32_to_bf16(acc[i][1]);
                o.z = f32_to_bf16(acc[i][2]);
                o.w = f32_to_bf16(acc[i][3]);
                *reinterpret_cast<ushort4*>((unsigned short*)out + (size_t)r * 64 + cc) = o;
            } else {
                float4 o = make_float4(acc[i][0], acc[i][1], acc[i][2], acc[i][3]);
                *reinterpret_cast<float4*>((float*)out + (size_t)r * 64 + cc) = o;
            }
        }
    }

    if (STATS) {
        float cs[4], cq[4];
        #pragma unroll
        for (int j = 0; j < 4; ++j) {
            cs[j] = 0.f; cq[j] = 0.f;
            #pragma unroll
            for (int i = 0; i < 4; ++i) {
                if (r0 + rr + i < N) {
                    float v = acc[i][j];
                    cs[j] += v; cq[j] += v * v;
                }
            }
        }
        __syncthreads();                 // done with sA; reuse as reduce buffer
        float* red = &sA[0][0];          // [16][64] dense
        const int g = tid >> 4;
        #pragma unroll
        for (int j = 0; j < 4; ++j) red[g * 64 + cc + j] = cs[j];
        __syncthreads();
        if (tid < 64) {
            float s = 0.f;
            #pragma unroll
            for (int g2 = 0; g2 < 16; ++g2) s += red[g2 * 64 + tid];
            atomicAdd(&stats[tid], s);
        }
        __syncthreads();
        #pragma unroll
        for (int j = 0; j < 4; ++j) red[g * 64 + cc + j] = cq[j];
        __syncthreads();
        if (tid < 64) {
            float q = 0.f;
            #pragma unroll
            for (int g2 = 0; g2 < 16; ++g2) q += red[g2 * 64 + tid];
            atomicAdd(&stats[64 + tid], q);
        }
    }
}

// ===========================================================================
// Gather-aggregate, packed-bf16 table (uint = 2 features), half-wave/edge:
//   mid[r] = relu((1+eps)*y[r] + sum_j w_j * y[src_j] + ba)
// lanes 0-31 handle even edges, 32-63 odd; merged via shfl_xor(32).
// ===========================================================================
__global__ __launch_bounds__(256) void aggmid_kernel(
    const unsigned* __restrict__ yu,     // [N][32] packed bf16 pairs
    const int* __restrict__ row_start,
    const uint2* __restrict__ einfo,
    const float* __restrict__ epsp,
    const float* __restrict__ ba,
    float* __restrict__ mid, int N)
{
    const int lane = threadIdx.x & 63;
    const int half = lane >> 5;          // 0 or 1
    const int u    = lane & 31;          // feature-pair index
    int w  = (blockIdx.x * 256 + threadIdx.x) >> 6;
    const int nw = (gridDim.x * 256) >> 6;
    const float eps1 = 1.0f + epsp[0];
    const float2 bal = *reinterpret_cast<const float2*>(ba + 2 * u);

    for (int r = w; r < N; r += nw) {
        const int rs = row_start[r];
        const int re = row_start[r + 1];

        float a0 = 0.f, a1 = 0.f, b0 = 0.f, b1 = 0.f;
        int j = rs;
        for (; j + 4 <= re; j += 4) {
            uint2 pA = einfo[j + half];          // edges j / j+1
            uint2 pB = einfo[j + 2 + half];      // edges j+2 / j+3
            unsigned yA = yu[(size_t)pA.x * 32 + u];
            unsigned yB = yu[(size_t)pB.x * 32 + u];
            float wA = __uint_as_float(pA.y);
            float wB = __uint_as_float(pB.y);
            a0 = fmaf(wA, bf16_lo(yA), a0); a1 = fmaf(wA, bf16_hi(yA), a1);
            b0 = fmaf(wB, bf16_lo(yB), b0); b1 = fmaf(wB, bf16_hi(yB), b1);
        }
        for (; j < re; j += 2) {
            int e = j + half;
            bool valid = e < re;
            uint2 p = valid ? einfo[e] : make_uint2(0u, 0u);
            float wv = valid ? __uint_as_float(p.y) : 0.f;
            unsigned yv = yu[(size_t)p.x * 32 + u];
            a0 = fmaf(wv, bf16_lo(yv), a0); a1 = fmaf(wv, bf16_hi(yv), a1);
        }
        a0 += b0; a1 += b1;
        a0 += __shfl_xor(a0, 32);
        a1 += __shfl_xor(a1, 32);

        unsigned sv = yu[(size_t)r * 32 + u];
        float m0 = fmaf(eps1, bf16_lo(sv), a0) + bal.x;
        float m1 = fmaf(eps1, bf16_hi(sv), a1) + bal.y;
        if (half == 0) {
            float2 o = make_float2(fmaxf(m0, 0.f), fmaxf(m1, 0.f));
            *reinterpret_cast<float2*>(&mid[(size_t)r * 64 + 2 * u]) = o;
        }
    }
}

// ===========================================================================
// BN apply with fused finalize (+ReLU, optional residual, may alias in-place)
// ===========================================================================
template<int RES>
__global__ __launch_bounds__(256) void bn_apply(
    const float* __restrict__ h2, const float* __restrict__ stats,
    const float* __restrict__ g, const float* __restrict__ be,
    const float* res, float* out, int N, int n4)
{
    __shared__ float sab[128];
    int t = threadIdx.x;
    if (t < 64) {
        float invN = 1.0f / (float)N;
        float mean = stats[t] * invN;
        float var  = stats[64 + t] * invN - mean * mean;
        float a = g[t] * rsqrtf(var + BN_EPS);
        sab[t]      = a;
        sab[64 + t] = be[t] - mean * a;
    }
    __syncthreads();

    int i = blockIdx.x * blockDim.x + t;
    int stride = gridDim.x * blockDim.x;
    for (; i < n4; i += stride) {
        float4 v = reinterpret_cast<const float4*>(h2)[i];
        int l0 = (i * 4) & 63;
        float4 o;
        o.x = fmaxf(fmaf(v.x, sab[l0 + 0], sab[64 + l0 + 0]), 0.f);
        o.y = fmaxf(fmaf(v.y, sab[l0 + 1], sab[64 + l0 + 1]), 0.f);
        o.z = fmaxf(fmaf(v.z, sab[l0 + 2], sab[64 + l0 + 2]), 0.f);
        o.w = fmaxf(fmaf(v.w, sab[l0 + 3], sab[64 + l0 + 3]), 0.f);
        if (RES) {
            float4 rv = reinterpret_cast<const float4*>(res)[i];
            o.x += rv.x; o.y += rv.y; o.z += rv.z; o.w += rv.w;
        }
        reinterpret_cast<float4*>(out)[i] = o;
    }
}

// ===========================================================================
extern "C" void kernel_launch(void* const* d_in, const int* in_sizes, int n_in,
                              void* d_out, int out_size, void* d_ws, size_t ws_size,
                              hipStream_t stream)
{
    const float* x    = (const float*)d_in[0];
    const int*   ei   = (const int*)  d_in[1];
    const float* ew   = (const float*)d_in[2];
    const float* eps1 = (const float*)d_in[3];
    const float* W1a  = (const float*)d_in[4];
    const float* b1a  = (const float*)d_in[5];
    const float* W1b  = (const float*)d_in[6];
    const float* b1b  = (const float*)d_in[7];
    const float* g1   = (const float*)d_in[8];
    const float* be1  = (const float*)d_in[9];
    const float* epss = (const float*)d_in[10];
    const float* Wsa  = (const float*)d_in[11];
    const float* bsa  = (const float*)d_in[12];
    const float* Wsb  = (const float*)d_in[13];
    const float* bsb  = (const float*)d_in[14];
    const float* gs   = (const float*)d_in[15];
    const float* bes  = (const float*)d_in[16];

    const int N   = in_sizes[0] / 128;
    const int E   = in_sizes[2];
    const int Lm1 = in_sizes[10];
    const int* src  = ei;
    const int* dstp = ei + E;

    // ---- workspace layout ----
    char* ws = (char*)d_ws;
    size_t off = 0;
    uint2* einfo = (uint2*)(ws + off);   off += (size_t)E * 8;
    float* regA  = (float*)(ws + off);   off += (size_t)N * 128 * 4;  // bufX | bufY
    unsigned* ybf = (unsigned*)(ws + off); off += (size_t)N * 64 * 2; // packed bf16 pairs
    int*   rank  = (int*)  (ws + off);   off += (size_t)E * 4;
    int*   deg   = (int*)  (ws + off);   off += (size_t)N * 4;
    int*   row_start = (int*)(ws + off); off += (size_t)(N + 1) * 4;
    float* stats = (float*)(ws + off);   off += 128 * 4;
    int*   blockSums = (int*)(ws + off); off += 256 * 4;
    int*   blockOff  = (int*)(ws + off);
    float* outp  = (float*)d_out;
    float* bufX  = regA;                      // mid scratch (N*64 f32)
    float* bufY  = regA + (size_t)N * 64;     // h2 scratch (N*64 f32)

    const int n4   = N * 64 / 4;
    const int NB   = (N + 511) / 512;         // scan blocks
    const int NBLK = (N + 63) / 64;           // gemm row-tiles
    const int EB   = (E + 255) / 256;         // edge blocks (1 edge/thread)

    // ---- build CSR by dst (once per call, reused by all layers) ----
    hipMemsetAsync(deg, 0, (size_t)N * 4, stream);
    rank_kernel<<<EB, 256, 0, stream>>>(dstp, deg, rank, E);
    scan_part1<<<NB, 256, 0, stream>>>(deg, blockSums, N);
    scan_part2<<<1, 256, 0, stream>>>(blockSums, blockOff, NB);
    scan_part3<<<NB, 256, 0, stream>>>(deg, blockOff, row_start, N, E);
    fill_pass2<<<EB, 256, 0, stream>>>(src, dstp, ew, rank, row_start, einfo, E);

    // ---- layer 1 (F=128 -> 64) ----
    hipMemsetAsync(stats, 0, 128 * 4, stream);
    gemm64_kernel<128, true, false><<<NBLK, 256, 0, stream>>>(x, W1a, nullptr, ybf, nullptr, N);
    aggmid_kernel<<<2048, 256, 0, stream>>>(ybf, row_start, einfo, eps1, b1a, bufX, N);
    gemm64_kernel<64, false, true><<<NBLK, 256, 0, stream>>>(bufX, W1b, b1b, bufY, stats, N);
    bn_apply<0><<<2048, 256, 0, stream>>>(bufY, stats, g1, be1, nullptr, outp, N, n4);

    // ---- layers 2..L (64 -> 64, residual, in-place over outp) ----
    for (int i = 0; i < Lm1; ++i) {
        hipMemsetAsync(stats, 0, 128 * 4, stream);
        gemm64_kernel<64, true, false><<<NBLK, 256, 0, stream>>>(
            outp, Wsa + (size_t)i * 64 * 64, nullptr, ybf, nullptr, N);
        aggmid_kernel<<<2048, 256, 0, stream>>>(
            ybf, row_start, einfo, epss + i, bsa + (size_t)i * 64, bufX, N);
        gemm64_kernel<64, false, true><<<NBLK, 256, 0, stream>>>(
            bufX, Wsb + (size_t)i * 64 * 64, bsb + (size_t)i * 64, bufY, stats, N);
        bn_apply<1><<<2048, 256, 0, stream>>>(bufY, stats,
            gs + (size_t)i * 64, bes + (size_t)i * 64, outp, outp, N, n4);
    }
}

// Round 11
// 547.995 us; speedup vs baseline: 1.0681x; 1.0681x over previous
//
#include <hip/hip_runtime.h>

#define BN_EPS 1e-5f

typedef __attribute__((ext_vector_type(8))) short bf16x8;
typedef __attribute__((ext_vector_type(4))) float f32x4;

__device__ __forceinline__ unsigned short f32_to_bf16(float f) {
    unsigned u = __float_as_uint(f);
    u += 0x7fffu + ((u >> 16) & 1u);   // round to nearest even
    return (unsigned short)(u >> 16);
}
__device__ __forceinline__ float bf16_lo(unsigned v) { return __uint_as_float(v << 16); }
__device__ __forceinline__ float bf16_hi(unsigned v) { return __uint_as_float(v & 0xffff0000u); }

// ===========================================================================
// CSR construction (by dst): rank pass -> 3-phase scan -> atomic-free fill
// ===========================================================================
__global__ __launch_bounds__(256) void rank_kernel(
    const int* __restrict__ dst, int* __restrict__ deg,
    int* __restrict__ rank, int E)
{
    int i = blockIdx.x * 256 + threadIdx.x;
    if (i < E) rank[i] = atomicAdd(&deg[dst[i]], 1);
}

__global__ __launch_bounds__(256) void scan_part1(
    const int* __restrict__ deg, int* __restrict__ blockSums, int N)
{
    __shared__ int sm[256];
    int t = threadIdx.x;
    int i0 = blockIdx.x * 512 + t * 2;
    int a = (i0     < N) ? deg[i0]     : 0;
    int b = (i0 + 1 < N) ? deg[i0 + 1] : 0;
    sm[t] = a + b;
    __syncthreads();
    for (int off = 128; off > 0; off >>= 1) {
        if (t < off) sm[t] += sm[t + off];
        __syncthreads();
    }
    if (t == 0) blockSums[blockIdx.x] = sm[0];
}

__global__ __launch_bounds__(256) void scan_part2(
    const int* __restrict__ blockSums, int* __restrict__ blockOff, int NB)
{
    __shared__ int sm[256];
    int t = threadIdx.x;
    sm[t] = (t < NB) ? blockSums[t] : 0;
    __syncthreads();
    for (int off = 1; off < 256; off <<= 1) {
        int v = (t >= off) ? sm[t - off] : 0;
        __syncthreads();
        sm[t] += v;
        __syncthreads();
    }
    if (t < NB) blockOff[t] = (t > 0) ? sm[t - 1] : 0;
}

__global__ __launch_bounds__(256) void scan_part3(
    const int* __restrict__ deg, const int* __restrict__ blockOff,
    int* __restrict__ row_start, int N, int E)
{
    __shared__ int sm[256];
    int t = threadIdx.x;
    int i0 = blockIdx.x * 512 + t * 2;
    int a = (i0     < N) ? deg[i0]     : 0;
    int b = (i0 + 1 < N) ? deg[i0 + 1] : 0;
    sm[t] = a + b;
    __syncthreads();
    for (int off = 1; off < 256; off <<= 1) {
        int v = (t >= off) ? sm[t - off] : 0;
        __syncthreads();
        sm[t] += v;
        __syncthreads();
    }
    int excl = blockOff[blockIdx.x] + ((t > 0) ? sm[t - 1] : 0);
    if (i0 < N)     row_start[i0]     = excl;
    if (i0 + 1 < N) row_start[i0 + 1] = excl + a;
    if (blockIdx.x == 0 && t == 0) row_start[N] = E;
}

__global__ __launch_bounds__(256) void fill_pass2(
    const int* __restrict__ src, const int* __restrict__ dst,
    const float* __restrict__ ew, const int* __restrict__ rank,
    const int* __restrict__ row_start, uint2* __restrict__ einfo, int E)
{
    int i = blockIdx.x * 256 + threadIdx.x;
    if (i < E) {
        int pos = row_start[dst[i]] + rank[i];
        uint2 p;
        p.x = (unsigned)src[i];
        p.y = __float_as_uint(ew[i]);
        einfo[pos] = p;
    }
}

// ===========================================================================
// Pack weight matrices into MFMA B-fragment layout (bf16).
// Frag element: ushort idx = ((n*KS+ks)*64 + l)*8 + j  <-  W[k][c],
//   k = ks*32 + (l>>4)*8 + j,  c = n*16 + (l&15).
// wf layout: [0,8192) W1a (KS=4); [8192,12288) W1b; then per layer i:
//   12288 + i*8192 + {0: Wsa_i, 4096: Wsb_i}
// Grid: 4 + 2 + 4*Lm1 blocks; each block packs a 2048-element chunk.
// ===========================================================================
__global__ __launch_bounds__(256) void prep_wfrag(
    const float* __restrict__ W1a, const float* __restrict__ W1b,
    const float* __restrict__ Wsa, const float* __restrict__ Wsb,
    unsigned short* __restrict__ wf)
{
    int bid = blockIdx.x;
    const float* src; unsigned short* dst; int KS, chunk;
    if (bid < 4)      { src = W1a; dst = wf;        KS = 4; chunk = bid; }
    else if (bid < 6) { src = W1b; dst = wf + 8192; KS = 2; chunk = bid - 4; }
    else {
        int t = bid - 6;
        int layer = t >> 2;
        int wh = (t >> 1) & 1;           // 0 = Wsa, 1 = Wsb
        chunk = t & 1;
        src = (wh ? Wsb : Wsa) + (size_t)layer * 4096;
        dst = wf + 12288 + layer * 8192 + wh * 4096;
        KS = 2;
    }
    int base = chunk * 2048;
    for (int e = base + threadIdx.x; e < base + 2048; e += 256) {
        int j  = e & 7;
        int l  = (e >> 3) & 63;
        int nk = e >> 9;                 // n*KS + ks
        int ks = nk % KS, n = nk / KS;
        int k  = ks * 32 + ((l >> 4) << 3) + j;
        int c  = n * 16 + (l & 15);
        dst[e] = f32_to_bf16(src[k * 64 + c]);
    }
}

// ===========================================================================
// MFMA GEMM: out[N][64] = A[N][K] @ W[K][64] (+bias)
// 64 rows/block, 4 waves; wave w: rows [w*16, w*16+16) x all 64 cols
// = 4 mfma_f32_16x16x32_bf16 per k-step. B-frags read from global (L2).
// A16: A is packed bf16 pairs [N][K/2] uint. Else f32 (converted on stage).
// BF16OUT: packed-bf16 output table. STATS: fused BN sum/sumsq.
// ===========================================================================
template<int KS, bool A16, bool BF16OUT, bool STATS>
__global__ __launch_bounds__(256) void gemm_mfma(
    const void* __restrict__ Ain, const bf16x8* __restrict__ wfrag,
    const float* __restrict__ bias, void* __restrict__ out,
    float* __restrict__ stats, int N)
{
    constexpr int K   = KS * 32;
    constexpr int LDA = K + 8;                 // ushorts/row: 16B-aligned stride
    __shared__ __align__(16) unsigned short sA[64 * LDA];

    const int tid = threadIdx.x;
    const int r0  = blockIdx.x * 64;

    if (A16) {
        const uint4* Au = (const uint4*)Ain;   // [N][K/8] uint4
        constexpr int C16 = K / 8;
        for (int i = tid; i < 64 * C16; i += 256) {
            int r = i / C16, c = i % C16;
            uint4 v = make_uint4(0u, 0u, 0u, 0u);
            if (r0 + r < N) v = Au[(size_t)(r0 + r) * C16 + c];
            *reinterpret_cast<uint4*>(&sA[r * LDA + c * 8]) = v;
        }
    } else {
        const float* Af = (const float*)Ain;
        constexpr int C4 = K / 4;
        for (int i = tid; i < 64 * C4; i += 256) {
            int r = i / C4, c4 = i % C4;
            float4 v = make_float4(0.f, 0.f, 0.f, 0.f);
            if (r0 + r < N)
                v = reinterpret_cast<const float4*>(Af + (size_t)(r0 + r) * K)[c4];
            ushort4 pk;
            pk.x = f32_to_bf16(v.x); pk.y = f32_to_bf16(v.y);
            pk.z = f32_to_bf16(v.z); pk.w = f32_to_bf16(v.w);
            *reinterpret_cast<ushort4*>(&sA[r * LDA + c4 * 4]) = pk;
        }
    }
    __syncthreads();

    const int w  = tid >> 6;
    const int l  = tid & 63;
    const int lr = l & 15;      // A row within slab / output col within tile
    const int lg = l >> 4;      // k-group / output row-group

    f32x4 acc0 = {0.f,0.f,0.f,0.f}, acc1 = {0.f,0.f,0.f,0.f};
    f32x4 acc2 = {0.f,0.f,0.f,0.f}, acc3 = {0.f,0.f,0.f,0.f};

    #pragma unroll
    for (int ks = 0; ks < KS; ++ks) {
        bf16x8 af = *reinterpret_cast<const bf16x8*>(
            &sA[(w * 16 + lr) * LDA + ks * 32 + lg * 8]);
        acc0 = __builtin_amdgcn_mfma_f32_16x16x32_bf16(af, wfrag[(0 * KS + ks) * 64 + l], acc0, 0, 0, 0);
        acc1 = __builtin_amdgcn_mfma_f32_16x16x32_bf16(af, wfrag[(1 * KS + ks) * 64 + l], acc1, 0, 0, 0);
        acc2 = __builtin_amdgcn_mfma_f32_16x16x32_bf16(af, wfrag[(2 * KS + ks) * 64 + l], acc2, 0, 0, 0);
        acc3 = __builtin_amdgcn_mfma_f32_16x16x32_bf16(af, wfrag[(3 * KS + ks) * 64 + l], acc3, 0, 0, 0);
    }

    const int rbase = r0 + w * 16 + lg * 4;
    float cs[4], cq[4];
    #pragma unroll
    for (int n = 0; n < 4; ++n) {
        float bv = bias ? bias[n * 16 + lr] : 0.f;
        f32x4 a = (n == 0) ? acc0 : (n == 1) ? acc1 : (n == 2) ? acc2 : acc3;
        cs[n] = 0.f; cq[n] = 0.f;
        #pragma unroll
        for (int j = 0; j < 4; ++j) {
            float v = a[j] + bv;
            int r = rbase + j;
            if (r < N) {
                if (BF16OUT)
                    ((unsigned short*)out)[(size_t)r * 64 + n * 16 + lr] = f32_to_bf16(v);
                else
                    ((float*)out)[(size_t)r * 64 + n * 16 + lr] = v;
                if (STATS) { cs[n] += v; cq[n] += v * v; }
            }
        }
    }

    if (STATS) {
        __syncthreads();                       // done with sA; reuse as f32 buffer
        float* red = reinterpret_cast<float*>(sA);   // needs 16*64*4 = 4KB (sA >= 9KB)
        int g = w * 4 + lg;
        #pragma unroll
        for (int n = 0; n < 4; ++n) red[g * 64 + n * 16 + lr] = cs[n];
        __syncthreads();
        if (tid < 64) {
            float s = 0.f;
            #pragma unroll
            for (int g2 = 0; g2 < 16; ++g2) s += red[g2 * 64 + tid];
            atomicAdd(&stats[tid], s);
        }
        __syncthreads();
        #pragma unroll
        for (int n = 0; n < 4; ++n) red[g * 64 + n * 16 + lr] = cq[n];
        __syncthreads();
        if (tid < 64) {
            float q = 0.f;
            #pragma unroll
            for (int g2 = 0; g2 < 16; ++g2) q += red[g2 * 64 + tid];
            atomicAdd(&stats[64 + tid], q);
        }
    }
}

// ===========================================================================
// Gather-aggregate, packed-bf16 table in AND out, half-wave per edge:
//   mid[r] = relu((1+eps)*y[r] + sum_j w_j * y[src_j] + ba)   (packed bf16)
// ===========================================================================
__global__ __launch_bounds__(256) void aggmid_kernel(
    const unsigned* __restrict__ yu,     // [N][32] packed bf16 pairs
    const int* __restrict__ row_start,
    const uint2* __restrict__ einfo,
    const float* __restrict__ epsp,
    const float* __restrict__ ba,
    unsigned* __restrict__ midu, int N)  // [N][32] packed bf16 pairs
{
    const int lane = threadIdx.x & 63;
    const int half = lane >> 5;
    const int u    = lane & 31;
    int w  = (blockIdx.x * 256 + threadIdx.x) >> 6;
    const int nw = (gridDim.x * 256) >> 6;
    const float eps1 = 1.0f + epsp[0];
    const float2 bal = *reinterpret_cast<const float2*>(ba + 2 * u);

    for (int r = w; r < N; r += nw) {
        const int rs = row_start[r];
        const int re = row_start[r + 1];

        float a0 = 0.f, a1 = 0.f, b0 = 0.f, b1 = 0.f;
        int j = rs;
        for (; j + 4 <= re; j += 4) {
            uint2 pA = einfo[j + half];
            uint2 pB = einfo[j + 2 + half];
            unsigned yA = yu[(size_t)pA.x * 32 + u];
            unsigned yB = yu[(size_t)pB.x * 32 + u];
            float wA = __uint_as_float(pA.y);
            float wB = __uint_as_float(pB.y);
            a0 = fmaf(wA, bf16_lo(yA), a0); a1 = fmaf(wA, bf16_hi(yA), a1);
            b0 = fmaf(wB, bf16_lo(yB), b0); b1 = fmaf(wB, bf16_hi(yB), b1);
        }
        for (; j < re; j += 2) {
            int e = j + half;
            bool valid = e < re;
            uint2 p = valid ? einfo[e] : make_uint2(0u, 0u);
            float wv = valid ? __uint_as_float(p.y) : 0.f;
            unsigned yv = yu[(size_t)p.x * 32 + u];
            a0 = fmaf(wv, bf16_lo(yv), a0); a1 = fmaf(wv, bf16_hi(yv), a1);
        }
        a0 += b0; a1 += b1;
        a0 += __shfl_xor(a0, 32);
        a1 += __shfl_xor(a1, 32);

        unsigned sv = yu[(size_t)r * 32 + u];
        float m0 = fmaf(eps1, bf16_lo(sv), a0) + bal.x;
        float m1 = fmaf(eps1, bf16_hi(sv), a1) + bal.y;
        if (half == 0) {
            unsigned pk = (unsigned)f32_to_bf16(fmaxf(m0, 0.f))
                        | ((unsigned)f32_to_bf16(fmaxf(m1, 0.f)) << 16);
            midu[(size_t)r * 32 + u] = pk;
        }
    }
}

// ===========================================================================
// BN apply with fused finalize (+ReLU, optional residual, may alias in-place)
// ===========================================================================
template<int RES>
__global__ __launch_bounds__(256) void bn_apply(
    const float* __restrict__ h2, const float* __restrict__ stats,
    const float* __restrict__ g, const float* __restrict__ be,
    const float* res, float* out, int N, int n4)
{
    __shared__ float sab[128];
    int t = threadIdx.x;
    if (t < 64) {
        float invN = 1.0f / (float)N;
        float mean = stats[t] * invN;
        float var  = stats[64 + t] * invN - mean * mean;
        float a = g[t] * rsqrtf(var + BN_EPS);
        sab[t]      = a;
        sab[64 + t] = be[t] - mean * a;
    }
    __syncthreads();

    int i = blockIdx.x * blockDim.x + t;
    int stride = gridDim.x * blockDim.x;
    for (; i < n4; i += stride) {
        float4 v = reinterpret_cast<const float4*>(h2)[i];
        int l0 = (i * 4) & 63;
        float4 o;
        o.x = fmaxf(fmaf(v.x, sab[l0 + 0], sab[64 + l0 + 0]), 0.f);
        o.y = fmaxf(fmaf(v.y, sab[l0 + 1], sab[64 + l0 + 1]), 0.f);
        o.z = fmaxf(fmaf(v.z, sab[l0 + 2], sab[64 + l0 + 2]), 0.f);
        o.w = fmaxf(fmaf(v.w, sab[l0 + 3], sab[64 + l0 + 3]), 0.f);
        if (RES) {
            float4 rv = reinterpret_cast<const float4*>(res)[i];
            o.x += rv.x; o.y += rv.y; o.z += rv.z; o.w += rv.w;
        }
        reinterpret_cast<float4*>(out)[i] = o;
    }
}

// ===========================================================================
extern "C" void kernel_launch(void* const* d_in, const int* in_sizes, int n_in,
                              void* d_out, int out_size, void* d_ws, size_t ws_size,
                              hipStream_t stream)
{
    const float* x    = (const float*)d_in[0];
    const int*   ei   = (const int*)  d_in[1];
    const float* ew   = (const float*)d_in[2];
    const float* eps1 = (const float*)d_in[3];
    const float* W1a  = (const float*)d_in[4];
    const float* b1a  = (const float*)d_in[5];
    const float* W1b  = (const float*)d_in[6];
    const float* b1b  = (const float*)d_in[7];
    const float* g1   = (const float*)d_in[8];
    const float* be1  = (const float*)d_in[9];
    const float* epss = (const float*)d_in[10];
    const float* Wsa  = (const float*)d_in[11];
    const float* bsa  = (const float*)d_in[12];
    const float* Wsb  = (const float*)d_in[13];
    const float* bsb  = (const float*)d_in[14];
    const float* gs   = (const float*)d_in[15];
    const float* bes  = (const float*)d_in[16];

    const int N   = in_sizes[0] / 128;
    const int E   = in_sizes[2];
    const int Lm1 = in_sizes[10];
    const int* src  = ei;
    const int* dstp = ei + E;

    // ---- workspace layout ----
    char* ws = (char*)d_ws;
    size_t off = 0;
    uint2* einfo = (uint2*)(ws + off);   off += (size_t)E * 8;
    float* regA  = (float*)(ws + off);   off += (size_t)N * 128 * 4;
    unsigned* ybf = (unsigned*)(ws + off); off += (size_t)N * 32 * 4; // [N][32] packed
    int*   rank  = (int*)  (ws + off);   off += (size_t)E * 4;
    int*   deg   = (int*)  (ws + off);   off += (size_t)N * 4;
    int*   row_start = (int*)(ws + off); off += (size_t)(N + 1) * 4;
    float* stats = (float*)(ws + off);   off += 128 * 4;
    int*   blockSums = (int*)(ws + off); off += 256 * 4;
    int*   blockOff  = (int*)(ws + off); off += 256 * 4;
    off = (off + 15) & ~(size_t)15;
    unsigned short* wf = (unsigned short*)(ws + off);  // 12288 + Lm1*8192 ushorts
    float* outp  = (float*)d_out;
    float* bufY  = regA;                               // h2 scratch (N*64 f32)
    unsigned* midu = (unsigned*)(regA + (size_t)N * 64); // [N][32] packed bf16

    const int n4   = N * 64 / 4;
    const int NB   = (N + 511) / 512;
    const int NBLK = (N + 63) / 64;
    const int EB   = (E + 255) / 256;

    // ---- pack weights into MFMA frag layout (once per call) ----
    prep_wfrag<<<6 + 4 * Lm1, 256, 0, stream>>>(W1a, W1b, Wsa, Wsb, wf);

    // ---- build CSR by dst (once per call, reused by all layers) ----
    hipMemsetAsync(deg, 0, (size_t)N * 4, stream);
    rank_kernel<<<EB, 256, 0, stream>>>(dstp, deg, rank, E);
    scan_part1<<<NB, 256, 0, stream>>>(deg, blockSums, N);
    scan_part2<<<1, 256, 0, stream>>>(blockSums, blockOff, NB);
    scan_part3<<<NB, 256, 0, stream>>>(deg, blockOff, row_start, N, E);
    fill_pass2<<<EB, 256, 0, stream>>>(src, dstp, ew, rank, row_start, einfo, E);

    const bf16x8* wfA1 = (const bf16x8*)wf;
    const bf16x8* wfB1 = (const bf16x8*)(wf + 8192);

    // ---- layer 1 (F=128 -> 64) ----
    hipMemsetAsync(stats, 0, 128 * 4, stream);
    gemm_mfma<4, false, true, false><<<NBLK, 256, 0, stream>>>(x, wfA1, nullptr, ybf, nullptr, N);
    aggmid_kernel<<<2048, 256, 0, stream>>>(ybf, row_start, einfo, eps1, b1a, midu, N);
    gemm_mfma<2, true, false, true><<<NBLK, 256, 0, stream>>>(midu, wfB1, b1b, bufY, stats, N);
    bn_apply<0><<<2048, 256, 0, stream>>>(bufY, stats, g1, be1, nullptr, outp, N, n4);

    // ---- layers 2..L (64 -> 64, residual, in-place over outp) ----
    for (int i = 0; i < Lm1; ++i) {
        const bf16x8* wfAi = (const bf16x8*)(wf + 12288 + i * 8192);
        const bf16x8* wfBi = (const bf16x8*)(wf + 12288 + i * 8192 + 4096);
        hipMemsetAsync(stats, 0, 128 * 4, stream);
        gemm_mfma<2, false, true, false><<<NBLK, 256, 0, stream>>>(
            outp, wfAi, nullptr, ybf, nullptr, N);
        aggmid_kernel<<<2048, 256, 0, stream>>>(
            ybf, row_start, einfo, epss + i, bsa + (size_t)i * 64, midu, N);
        gemm_mfma<2, true, false, true><<<NBLK, 256, 0, stream>>>(
            midu, wfBi, bsb + (size_t)i * 64, bufY, stats, N);
        bn_apply<1><<<2048, 256, 0, stream>>>(bufY, stats,
            gs + (size_t)i * 64, bes + (size_t)i * 64, outp, outp, N, n4);
    }
}

// Round 12
// 539.438 us; speedup vs baseline: 1.0851x; 1.0159x over previous
//
#include <hip/hip_runtime.h>

#define BN_EPS 1e-5f

typedef __attribute__((ext_vector_type(8))) short bf16x8;
typedef __attribute__((ext_vector_type(4))) float f32x4;

__device__ __forceinline__ unsigned short f32_to_bf16(float f) {
    unsigned u = __float_as_uint(f);
    u += 0x7fffu + ((u >> 16) & 1u);   // round to nearest even
    return (unsigned short)(u >> 16);
}
__device__ __forceinline__ float bf16_lo(unsigned v) { return __uint_as_float(v << 16); }
__device__ __forceinline__ float bf16_hi(unsigned v) { return __uint_as_float(v & 0xffff0000u); }

// ===========================================================================
// CSR construction (by dst): rank pass -> 3-phase scan -> atomic-free fill
// ===========================================================================
__global__ __launch_bounds__(256) void rank_kernel(
    const int* __restrict__ dst, int* __restrict__ deg,
    int* __restrict__ rank, int E)
{
    int i = blockIdx.x * 256 + threadIdx.x;
    if (i < E) rank[i] = atomicAdd(&deg[dst[i]], 1);
}

__global__ __launch_bounds__(256) void scan_part1(
    const int* __restrict__ deg, int* __restrict__ blockSums, int N)
{
    __shared__ int sm[256];
    int t = threadIdx.x;
    int i0 = blockIdx.x * 512 + t * 2;
    int a = (i0     < N) ? deg[i0]     : 0;
    int b = (i0 + 1 < N) ? deg[i0 + 1] : 0;
    sm[t] = a + b;
    __syncthreads();
    for (int off = 128; off > 0; off >>= 1) {
        if (t < off) sm[t] += sm[t + off];
        __syncthreads();
    }
    if (t == 0) blockSums[blockIdx.x] = sm[0];
}

__global__ __launch_bounds__(256) void scan_part2(
    const int* __restrict__ blockSums, int* __restrict__ blockOff, int NB)
{
    __shared__ int sm[256];
    int t = threadIdx.x;
    sm[t] = (t < NB) ? blockSums[t] : 0;
    __syncthreads();
    for (int off = 1; off < 256; off <<= 1) {
        int v = (t >= off) ? sm[t - off] : 0;
        __syncthreads();
        sm[t] += v;
        __syncthreads();
    }
    if (t < NB) blockOff[t] = (t > 0) ? sm[t - 1] : 0;
}

__global__ __launch_bounds__(256) void scan_part3(
    const int* __restrict__ deg, const int* __restrict__ blockOff,
    int* __restrict__ row_start, int N, int E)
{
    __shared__ int sm[256];
    int t = threadIdx.x;
    int i0 = blockIdx.x * 512 + t * 2;
    int a = (i0     < N) ? deg[i0]     : 0;
    int b = (i0 + 1 < N) ? deg[i0 + 1] : 0;
    sm[t] = a + b;
    __syncthreads();
    for (int off = 1; off < 256; off <<= 1) {
        int v = (t >= off) ? sm[t - off] : 0;
        __syncthreads();
        sm[t] += v;
        __syncthreads();
    }
    int excl = blockOff[blockIdx.x] + ((t > 0) ? sm[t - 1] : 0);
    if (i0 < N)     row_start[i0]     = excl;
    if (i0 + 1 < N) row_start[i0 + 1] = excl + a;
    if (blockIdx.x == 0 && t == 0) row_start[N] = E;
}

__global__ __launch_bounds__(256) void fill_pass2(
    const int* __restrict__ src, const int* __restrict__ dst,
    const float* __restrict__ ew, const int* __restrict__ rank,
    const int* __restrict__ row_start, uint2* __restrict__ einfo, int E)
{
    int i = blockIdx.x * 256 + threadIdx.x;
    if (i < E) {
        int pos = row_start[dst[i]] + rank[i];
        uint2 p;
        p.x = (unsigned)src[i];
        p.y = __float_as_uint(ew[i]);
        einfo[pos] = p;
    }
}

// ===========================================================================
// Pack weight matrices into MFMA B-fragment layout (bf16).
// ushort idx = ((n*KS+ks)*64 + l)*8 + j  <-  W[k][c],
//   k = ks*32 + (l>>4)*8 + j,  c = n*16 + (l&15).
// ===========================================================================
__global__ __launch_bounds__(256) void prep_wfrag(
    const float* __restrict__ W1a, const float* __restrict__ W1b,
    const float* __restrict__ Wsa, const float* __restrict__ Wsb,
    unsigned short* __restrict__ wf)
{
    int bid = blockIdx.x;
    const float* src; unsigned short* dst; int KS, chunk;
    if (bid < 4)      { src = W1a; dst = wf;        KS = 4; chunk = bid; }
    else if (bid < 6) { src = W1b; dst = wf + 8192; KS = 2; chunk = bid - 4; }
    else {
        int t = bid - 6;
        int layer = t >> 2;
        int wh = (t >> 1) & 1;
        chunk = t & 1;
        src = (wh ? Wsb : Wsa) + (size_t)layer * 4096;
        dst = wf + 12288 + layer * 8192 + wh * 4096;
        KS = 2;
    }
    int base = chunk * 2048;
    for (int e = base + threadIdx.x; e < base + 2048; e += 256) {
        int j  = e & 7;
        int l  = (e >> 3) & 63;
        int nk = e >> 9;
        int ks = nk % KS, n = nk / KS;
        int k  = ks * 32 + ((l >> 4) << 3) + j;
        int c  = n * 16 + (l & 15);
        dst[e] = f32_to_bf16(src[k * 64 + c]);
    }
}

// ===========================================================================
// MFMA GEMM: out[N][64] = A[N][K] @ W[K][64] (+bias)
// 64 rows/block, 4 waves; W-frags staged in LDS; epilogue routed through LDS
// for fully-coalesced stores. A16: A packed bf16 [N][K/2] uint; else f32.
// ===========================================================================
template<int KS, bool A16, bool BF16OUT, bool STATS>
__global__ __launch_bounds__(256) void gemm_mfma(
    const void* __restrict__ Ain, const unsigned short* __restrict__ wfrag,
    const float* __restrict__ bias, void* __restrict__ out,
    float* __restrict__ stats, int N)
{
    constexpr int K   = KS * 32;
    constexpr int LDA = K + 8;                 // ushorts/row (16B-aligned stride)
    __shared__ __align__(16) unsigned short sA[64 * LDA];
    __shared__ __align__(16) unsigned short sB[4 * KS * 64 * 8];

    const int tid = threadIdx.x;
    const int r0  = blockIdx.x * 64;

    // stage B fragments (4*KS*64 uint4)
    {
        const uint4* sv = (const uint4*)wfrag;
        uint4* dv = (uint4*)sB;
        for (int i = tid; i < 4 * KS * 64; i += 256) dv[i] = sv[i];
    }
    // stage A tile
    if (A16) {
        const uint4* Au = (const uint4*)Ain;
        constexpr int C16 = K / 8;
        for (int i = tid; i < 64 * C16; i += 256) {
            int r = i / C16, c = i % C16;
            uint4 v = make_uint4(0u, 0u, 0u, 0u);
            if (r0 + r < N) v = Au[(size_t)(r0 + r) * C16 + c];
            *reinterpret_cast<uint4*>(&sA[r * LDA + c * 8]) = v;
        }
    } else {
        const float* Af = (const float*)Ain;
        constexpr int C4 = K / 4;
        for (int i = tid; i < 64 * C4; i += 256) {
            int r = i / C4, c4 = i % C4;
            float4 v = make_float4(0.f, 0.f, 0.f, 0.f);
            if (r0 + r < N)
                v = reinterpret_cast<const float4*>(Af + (size_t)(r0 + r) * K)[c4];
            ushort4 pk;
            pk.x = f32_to_bf16(v.x); pk.y = f32_to_bf16(v.y);
            pk.z = f32_to_bf16(v.z); pk.w = f32_to_bf16(v.w);
            *reinterpret_cast<ushort4*>(&sA[r * LDA + c4 * 4]) = pk;
        }
    }
    __syncthreads();

    const int w  = tid >> 6;
    const int l  = tid & 63;
    const int lr = l & 15;      // output col within 16-tile / A row within slab
    const int lg = l >> 4;      // k-group / output row-group

    f32x4 acc0 = {0.f,0.f,0.f,0.f}, acc1 = {0.f,0.f,0.f,0.f};
    f32x4 acc2 = {0.f,0.f,0.f,0.f}, acc3 = {0.f,0.f,0.f,0.f};

    #pragma unroll
    for (int ks = 0; ks < KS; ++ks) {
        bf16x8 af = *reinterpret_cast<const bf16x8*>(
            &sA[(w * 16 + lr) * LDA + ks * 32 + lg * 8]);
        bf16x8 b0 = *reinterpret_cast<const bf16x8*>(&sB[((0 * KS + ks) * 64 + l) * 8]);
        bf16x8 b1 = *reinterpret_cast<const bf16x8*>(&sB[((1 * KS + ks) * 64 + l) * 8]);
        bf16x8 b2 = *reinterpret_cast<const bf16x8*>(&sB[((2 * KS + ks) * 64 + l) * 8]);
        bf16x8 b3 = *reinterpret_cast<const bf16x8*>(&sB[((3 * KS + ks) * 64 + l) * 8]);
        acc0 = __builtin_amdgcn_mfma_f32_16x16x32_bf16(af, b0, acc0, 0, 0, 0);
        acc1 = __builtin_amdgcn_mfma_f32_16x16x32_bf16(af, b1, acc1, 0, 0, 0);
        acc2 = __builtin_amdgcn_mfma_f32_16x16x32_bf16(af, b2, acc2, 0, 0, 0);
        acc3 = __builtin_amdgcn_mfma_f32_16x16x32_bf16(af, b3, acc3, 0, 0, 0);
    }

    // bias + stats partials in registers (C/D layout: col=n*16+lr, row=lg*4+j)
    const int rlocal = w * 16 + lg * 4;
    float v[4][4], cs[4], cq[4];
    #pragma unroll
    for (int n = 0; n < 4; ++n) {
        float bv = bias ? bias[n * 16 + lr] : 0.f;
        f32x4 a = (n == 0) ? acc0 : (n == 1) ? acc1 : (n == 2) ? acc2 : acc3;
        cs[n] = 0.f; cq[n] = 0.f;
        #pragma unroll
        for (int j = 0; j < 4; ++j) {
            float vv = a[j] + bv;
            v[n][j] = vv;
            if (STATS && (r0 + rlocal + j < N)) { cs[n] += vv; cq[n] += vv * vv; }
        }
    }

    __syncthreads();   // all waves done reading sA/sB

    if (BF16OUT) {
        // dump bf16 rows into sA at stride 72 (2-way bank alias only)
        #pragma unroll
        for (int n = 0; n < 4; ++n)
            #pragma unroll
            for (int j = 0; j < 4; ++j)
                sA[(rlocal + j) * 72 + n * 16 + lr] = f32_to_bf16(v[n][j]);
        __syncthreads();
        unsigned short* o = (unsigned short*)out;
        for (int i = tid; i < 64 * 8; i += 256) {
            int r = i >> 3, q = i & 7;
            if (r0 + r < N)
                *reinterpret_cast<uint4*>(o + (size_t)(r0 + r) * 64 + q * 8) =
                    *reinterpret_cast<const uint4*>(&sA[r * 72 + q * 8]);
        }
    } else {
        // f32 out via two 32-row rounds (stride-68 f32 LDS tile)
        float* o = (float*)out;
        float* sAf = reinterpret_cast<float*>(sA);
        #pragma unroll
        for (int half = 0; half < 2; ++half) {
            if ((w >> 1) == half) {
                #pragma unroll
                for (int n = 0; n < 4; ++n)
                    #pragma unroll
                    for (int j = 0; j < 4; ++j)
                        sAf[((w & 1) * 16 + lg * 4 + j) * 68 + n * 16 + lr] = v[n][j];
            }
            __syncthreads();
            for (int i = tid; i < 32 * 16; i += 256) {
                int r = i >> 4, c4 = i & 15;
                int gr = r0 + half * 32 + r;
                if (gr < N)
                    *reinterpret_cast<float4*>(o + (size_t)gr * 64 + c4 * 4) =
                        *reinterpret_cast<const float4*>(&sAf[r * 68 + c4 * 4]);
            }
            __syncthreads();
        }
    }

    if (STATS) {
        __syncthreads();
        float* red = reinterpret_cast<float*>(sA);   // 16x64 f32 = 4KB
        int g = w * 4 + lg;
        #pragma unroll
        for (int n = 0; n < 4; ++n) red[g * 64 + n * 16 + lr] = cs[n];
        __syncthreads();
        if (tid < 64) {
            float s = 0.f;
            #pragma unroll
            for (int g2 = 0; g2 < 16; ++g2) s += red[g2 * 64 + tid];
            atomicAdd(&stats[tid], s);
        }
        __syncthreads();
        #pragma unroll
        for (int n = 0; n < 4; ++n) red[g * 64 + n * 16 + lr] = cq[n];
        __syncthreads();
        if (tid < 64) {
            float q = 0.f;
            #pragma unroll
            for (int g2 = 0; g2 < 16; ++g2) q += red[g2 * 64 + tid];
            atomicAdd(&stats[64 + tid], q);
        }
    }
}

// ===========================================================================
// Gather-aggregate, packed-bf16 table in AND out, half-wave per edge:
//   mid[r] = relu((1+eps)*y[r] + sum_j w_j * y[src_j] + ba)
// ===========================================================================
__global__ __launch_bounds__(256) void aggmid_kernel(
    const unsigned* __restrict__ yu,
    const int* __restrict__ row_start,
    const uint2* __restrict__ einfo,
    const float* __restrict__ epsp,
    const float* __restrict__ ba,
    unsigned* __restrict__ midu, int N)
{
    const int lane = threadIdx.x & 63;
    const int half = lane >> 5;
    const int u    = lane & 31;
    int w  = (blockIdx.x * 256 + threadIdx.x) >> 6;
    const int nw = (gridDim.x * 256) >> 6;
    const float eps1 = 1.0f + epsp[0];
    const float2 bal = *reinterpret_cast<const float2*>(ba + 2 * u);

    for (int r = w; r < N; r += nw) {
        const int rs = row_start[r];
        const int re = row_start[r + 1];

        float a0 = 0.f, a1 = 0.f, b0 = 0.f, b1 = 0.f;
        int j = rs;
        for (; j + 4 <= re; j += 4) {
            uint2 pA = einfo[j + half];
            uint2 pB = einfo[j + 2 + half];
            unsigned yA = yu[(size_t)pA.x * 32 + u];
            unsigned yB = yu[(size_t)pB.x * 32 + u];
            float wA = __uint_as_float(pA.y);
            float wB = __uint_as_float(pB.y);
            a0 = fmaf(wA, bf16_lo(yA), a0); a1 = fmaf(wA, bf16_hi(yA), a1);
            b0 = fmaf(wB, bf16_lo(yB), b0); b1 = fmaf(wB, bf16_hi(yB), b1);
        }
        for (; j < re; j += 2) {
            int e = j + half;
            bool valid = e < re;
            uint2 p = valid ? einfo[e] : make_uint2(0u, 0u);
            float wv = valid ? __uint_as_float(p.y) : 0.f;
            unsigned yv = yu[(size_t)p.x * 32 + u];
            a0 = fmaf(wv, bf16_lo(yv), a0); a1 = fmaf(wv, bf16_hi(yv), a1);
        }
        a0 += b0; a1 += b1;
        a0 += __shfl_xor(a0, 32);
        a1 += __shfl_xor(a1, 32);

        unsigned sv = yu[(size_t)r * 32 + u];
        float m0 = fmaf(eps1, bf16_lo(sv), a0) + bal.x;
        float m1 = fmaf(eps1, bf16_hi(sv), a1) + bal.y;
        if (half == 0) {
            unsigned pk = (unsigned)f32_to_bf16(fmaxf(m0, 0.f))
                        | ((unsigned)f32_to_bf16(fmaxf(m1, 0.f)) << 16);
            midu[(size_t)r * 32 + u] = pk;
        }
    }
}

// ===========================================================================
// BN apply with fused finalize (+ReLU, optional residual, may alias in-place)
// ===========================================================================
template<int RES>
__global__ __launch_bounds__(256) void bn_apply(
    const float* __restrict__ h2, const float* __restrict__ stats,
    const float* __restrict__ g, const float* __restrict__ be,
    const float* res, float* out, int N, int n4)
{
    __shared__ float sab[128];
    int t = threadIdx.x;
    if (t < 64) {
        float invN = 1.0f / (float)N;
        float mean = stats[t] * invN;
        float var  = stats[64 + t] * invN - mean * mean;
        float a = g[t] * rsqrtf(var + BN_EPS);
        sab[t]      = a;
        sab[64 + t] = be[t] - mean * a;
    }
    __syncthreads();

    int i = blockIdx.x * blockDim.x + t;
    int stride = gridDim.x * blockDim.x;
    for (; i < n4; i += stride) {
        float4 v = reinterpret_cast<const float4*>(h2)[i];
        int l0 = (i * 4) & 63;
        float4 o;
        o.x = fmaxf(fmaf(v.x, sab[l0 + 0], sab[64 + l0 + 0]), 0.f);
        o.y = fmaxf(fmaf(v.y, sab[l0 + 1], sab[64 + l0 + 1]), 0.f);
        o.z = fmaxf(fmaf(v.z, sab[l0 + 2], sab[64 + l0 + 2]), 0.f);
        o.w = fmaxf(fmaf(v.w, sab[l0 + 3], sab[64 + l0 + 3]), 0.f);
        if (RES) {
            float4 rv = reinterpret_cast<const float4*>(res)[i];
            o.x += rv.x; o.y += rv.y; o.z += rv.z; o.w += rv.w;
        }
        reinterpret_cast<float4*>(out)[i] = o;
    }
}

// ===========================================================================
extern "C" void kernel_launch(void* const* d_in, const int* in_sizes, int n_in,
                              void* d_out, int out_size, void* d_ws, size_t ws_size,
                              hipStream_t stream)
{
    const float* x    = (const float*)d_in[0];
    const int*   ei   = (const int*)  d_in[1];
    const float* ew   = (const float*)d_in[2];
    const float* eps1 = (const float*)d_in[3];
    const float* W1a  = (const float*)d_in[4];
    const float* b1a  = (const float*)d_in[5];
    const float* W1b  = (const float*)d_in[6];
    const float* b1b  = (const float*)d_in[7];
    const float* g1   = (const float*)d_in[8];
    const float* be1  = (const float*)d_in[9];
    const float* epss = (const float*)d_in[10];
    const float* Wsa  = (const float*)d_in[11];
    const float* bsa  = (const float*)d_in[12];
    const float* Wsb  = (const float*)d_in[13];
    const float* bsb  = (const float*)d_in[14];
    const float* gs   = (const float*)d_in[15];
    const float* bes  = (const float*)d_in[16];

    const int N   = in_sizes[0] / 128;
    const int E   = in_sizes[2];
    const int Lm1 = in_sizes[10];
    const int* src  = ei;
    const int* dstp = ei + E;

    // ---- workspace layout ----
    char* ws = (char*)d_ws;
    size_t off = 0;
    uint2* einfo = (uint2*)(ws + off);   off += (size_t)E * 8;
    float* regA  = (float*)(ws + off);   off += (size_t)N * 128 * 4;
    unsigned* ybf = (unsigned*)(ws + off); off += (size_t)N * 32 * 4;
    int*   rank  = (int*)  (ws + off);   off += (size_t)E * 4;
    int*   deg   = (int*)  (ws + off);   off += (size_t)N * 4;
    int*   row_start = (int*)(ws + off); off += (size_t)(N + 1) * 4;
    float* stats = (float*)(ws + off);   off += 128 * 4;
    int*   blockSums = (int*)(ws + off); off += 256 * 4;
    int*   blockOff  = (int*)(ws + off); off += 256 * 4;
    off = (off + 15) & ~(size_t)15;
    unsigned short* wf = (unsigned short*)(ws + off);
    float* outp  = (float*)d_out;
    float* bufY  = regA;                               // h2 scratch (N*64 f32)
    unsigned* midu = (unsigned*)(regA + (size_t)N * 64);

    const int n4   = N * 64 / 4;
    const int NB   = (N + 511) / 512;
    const int NBLK = (N + 63) / 64;
    const int EB   = (E + 255) / 256;

    prep_wfrag<<<6 + 4 * Lm1, 256, 0, stream>>>(W1a, W1b, Wsa, Wsb, wf);

    hipMemsetAsync(deg, 0, (size_t)N * 4, stream);
    rank_kernel<<<EB, 256, 0, stream>>>(dstp, deg, rank, E);
    scan_part1<<<NB, 256, 0, stream>>>(deg, blockSums, N);
    scan_part2<<<1, 256, 0, stream>>>(blockSums, blockOff, NB);
    scan_part3<<<NB, 256, 0, stream>>>(deg, blockOff, row_start, N, E);
    fill_pass2<<<EB, 256, 0, stream>>>(src, dstp, ew, rank, row_start, einfo, E);

    const unsigned short* wfA1 = wf;
    const unsigned short* wfB1 = wf + 8192;

    // ---- layer 1 (F=128 -> 64) ----
    hipMemsetAsync(stats, 0, 128 * 4, stream);
    gemm_mfma<4, false, true, false><<<NBLK, 256, 0, stream>>>(x, wfA1, nullptr, ybf, nullptr, N);
    aggmid_kernel<<<2048, 256, 0, stream>>>(ybf, row_start, einfo, eps1, b1a, midu, N);
    gemm_mfma<2, true, false, true><<<NBLK, 256, 0, stream>>>(midu, wfB1, b1b, bufY, stats, N);
    bn_apply<0><<<2048, 256, 0, stream>>>(bufY, stats, g1, be1, nullptr, outp, N, n4);

    // ---- layers 2..L (64 -> 64, residual, in-place over outp) ----
    for (int i = 0; i < Lm1; ++i) {
        const unsigned short* wfAi = wf + 12288 + i * 8192;
        const unsigned short* wfBi = wf + 12288 + i * 8192 + 4096;
        hipMemsetAsync(stats, 0, 128 * 4, stream);
        gemm_mfma<2, false, true, false><<<NBLK, 256, 0, stream>>>(
            outp, wfAi, nullptr, ybf, nullptr, N);
        aggmid_kernel<<<2048, 256, 0, stream>>>(
            ybf, row_start, einfo, epss + i, bsa + (size_t)i * 64, midu, N);
        gemm_mfma<2, true, false, true><<<NBLK, 256, 0, stream>>>(
            midu, wfBi, bsb + (size_t)i * 64, bufY, stats, N);
        bn_apply<1><<<2048, 256, 0, stream>>>(bufY, stats,
            gs + (size_t)i * 64, bes + (size_t)i * 64, outp, outp, N, n4);
    }
}